// Round 3
// baseline (4306.628 us; speedup 1.0000x reference)
//
#include <hip/hip_runtime.h>
#include <hip/hip_fp16.h>

typedef _Float16 f16;
typedef __attribute__((ext_vector_type(8))) _Float16 f16x8;
typedef __attribute__((ext_vector_type(16))) float f32x16;

#define GLL(src, dst) __builtin_amdgcn_global_load_lds( \
    (const __attribute__((address_space(1))) void*)(src), \
    (__attribute__((address_space(3))) void*)(dst), 16, 0, 0)

// ---------------------------------------------------------------------------
// Core tile GEMM: C[128 x 128] = A[128 x K] * B(rows)[128 x K]^T
// using v_mfma_f32_32x32x16_f16. 4 waves, each owns a 64x64 quadrant
// (wr=wave>>1 rows, wc=wave&1 cols) as 2x2 32x32 tiles -> acc[2][2] f32x16.
// B tile row r -> global row nbase + (r>>5)*nstride + (r&31) (4 groups of 32).
//
// BK=64, double-buffered LDS (2 x (16KB A + 16KB B) = 64KB), depth-2 counted
// vmcnt prefetch (T3+T4), PLUS register-level fragment double-buffering:
// tile t+1's ds_reads issue before tile t's MFMAs, so LDS latency hides under
// the matrix pipe. Never vmcnt(0) in steady state.
//
// LDS layout: [row][8 chunks of 8 f16], chunk XOR (row&7); global source is
// pre-swizzled so global_load_lds dest stays linear (HW: base + lane*16).
// Frag read: lanes 0-7 hit 8 distinct chunk slots -> all 32 banks, no conflict.
//
// Operand layouts (verified lineage: 16x16x32 version passed in R1):
//   A/B frag: row = lane&31, k = (lane>>5)*8 + e, e contiguous (f16x8).
//   C/D:      col = lane&31, row = (reg&3) + 8*(reg>>2) + 4*(lane>>5).
// ---------------------------------------------------------------------------
__device__ __forceinline__ void gemm_core(
    const f16* __restrict__ A, int lda,
    const f16* __restrict__ Bm, int ldb,
    int K, int bm0, int nbase, int nstride,
    unsigned char* __restrict__ smem, f32x16 acc[2][2])
{
    const int tid  = threadIdx.x;
    const int wave = tid >> 6;
    const int wr   = wave >> 1;
    const int wc   = wave & 1;
    const int lane = tid & 63;
    const int l31  = lane & 31;
    const int hi   = lane >> 5;

    #pragma unroll
    for (int mt = 0; mt < 2; ++mt)
      #pragma unroll
      for (int nt = 0; nt < 2; ++nt)
        #pragma unroll
        for (int e = 0; e < 16; ++e)
          acc[mt][nt][e] = 0.f;

    // staging: A tile 128x64 f16 = 1024 chunks -> 4 passes; B same
    const f16* gA[4]; const f16* gB[4];
    int ldA[4], ldB[4];
    #pragma unroll
    for (int p = 0; p < 4; ++p) {
        int s  = p * 256 + tid;
        int r  = s >> 3;
        int cg = (s & 7) ^ (r & 7);            // pre-swizzled global chunk
        gA[p] = A + (size_t)(bm0 + r) * lda + cg * 8;
        int brow = nbase + (r >> 5) * nstride + (r & 31);
        gB[p] = Bm + (size_t)brow * ldb + cg * 8;
        ldA[p] = (p * 256 + wave * 64) * 16;   // linear dest, bytes
        ldB[p] = 16384 + (p * 256 + wave * 64) * 16;
    }

    // fragment offsets (f16 elements from buffer base); chunk c = kk*2 + hi
    int offA[2][4], offB[2][4];
    #pragma unroll
    for (int mt = 0; mt < 2; ++mt) {
        int ra = wr * 64 + mt * 32 + l31;
        #pragma unroll
        for (int kk = 0; kk < 4; ++kk)
            offA[mt][kk] = (ra * 8 + ((kk * 2 + hi) ^ (ra & 7))) * 8;
    }
    #pragma unroll
    for (int nt = 0; nt < 2; ++nt) {
        int rb = wc * 64 + nt * 32 + l31;
        #pragma unroll
        for (int kk = 0; kk < 4; ++kk)
            offB[nt][kk] = 8192 + (rb * 8 + ((kk * 2 + hi) ^ (rb & 7))) * 8;
    }

    auto stage = [&](int buf, int t2) {        // 8 loads per thread
        unsigned char* base = smem + buf * 32768;
        const int k0 = t2 * 64;
        #pragma unroll
        for (int p = 0; p < 4; ++p) GLL(gA[p] + k0, base + ldA[p]);
        #pragma unroll
        for (int p = 0; p < 4; ++p) GLL(gB[p] + k0, base + ldB[p]);
    };
    auto rdfr = [&](int buf, f16x8 (&af)[2][4], f16x8 (&bf)[2][4]) {
        const f16* base = (const f16*)(smem + buf * 32768);
        #pragma unroll
        for (int mt = 0; mt < 2; ++mt)
          #pragma unroll
          for (int kk = 0; kk < 4; ++kk)
            af[mt][kk] = *(const f16x8*)(base + offA[mt][kk]);
        #pragma unroll
        for (int nt = 0; nt < 2; ++nt)
          #pragma unroll
          for (int kk = 0; kk < 4; ++kk)
            bf[nt][kk] = *(const f16x8*)(base + offB[nt][kk]);
    };
    auto mm = [&](f16x8 (&af)[2][4], f16x8 (&bf)[2][4]) {
        #pragma unroll
        for (int kk = 0; kk < 4; ++kk)
          #pragma unroll
          for (int mt = 0; mt < 2; ++mt)
            #pragma unroll
            for (int nt = 0; nt < 2; ++nt)
              acc[mt][nt] = __builtin_amdgcn_mfma_f32_32x32x16_f16(
                  af[mt][kk], bf[nt][kk], acc[mt][nt], 0, 0, 0);
    };

    const int niter = K >> 6;                  // callers: K in {128, 2048} (even niter)
    f16x8 aX[2][4], bX[2][4], aY[2][4], bY[2][4];
    stage(0, 0);
    stage(1, 1);
    asm volatile("s_waitcnt vmcnt(8)" ::: "memory");   // tile 0 landed
    __builtin_amdgcn_s_barrier();
    __builtin_amdgcn_sched_barrier(0);
    rdfr(0, aX, bX);

    for (int t = 0; t < niter; t += 2) {
        // ---- sub-iter t (even): frags X, buf 0 ----
        asm volatile("s_waitcnt lgkmcnt(0)" ::: "memory");
        __builtin_amdgcn_sched_barrier(0);     // rule #18: fence MFMA hoisting
        __builtin_amdgcn_s_barrier();          // buf0 read-released
        __builtin_amdgcn_sched_barrier(0);
        if (t + 2 < niter) stage(0, t + 2);
        if (t + 2 < niter) asm volatile("s_waitcnt vmcnt(8)" ::: "memory");
        else               asm volatile("s_waitcnt vmcnt(0)" ::: "memory");
        __builtin_amdgcn_s_barrier();          // buf1 (tile t+1) ready
        __builtin_amdgcn_sched_barrier(0);
        rdfr(1, aY, bY);                       // reads overlap MFMAs below
        mm(aX, bX);
        // ---- sub-iter t+1 (odd): frags Y, buf 1 ----
        asm volatile("s_waitcnt lgkmcnt(0)" ::: "memory");
        __builtin_amdgcn_sched_barrier(0);     // rule #18
        __builtin_amdgcn_s_barrier();          // buf1 read-released
        __builtin_amdgcn_sched_barrier(0);
        if (t + 3 < niter) stage(1, t + 3);
        if (t + 2 < niter) {
            if (t + 3 < niter) asm volatile("s_waitcnt vmcnt(8)" ::: "memory");
            else               asm volatile("s_waitcnt vmcnt(0)" ::: "memory");
            __builtin_amdgcn_s_barrier();      // buf0 (tile t+2) ready
            __builtin_amdgcn_sched_barrier(0);
            rdfr(0, aX, bX);
        }
        mm(aY, bY);
    }
}

// ---------------------------------------------------------------------------
// One recurrent step (also step 0 with A=x0,K=128,W=W_ih):
//   gates = A @ W^T + bias ; cell ; write h (fp16) and c (fp32)
// Block: [128 batch x 32 hidden x 4 gates] (128 cols). Gates land in
// different waves, so exchange through LDS (G[128][128] f32, reuses the
// staging buffers) then each thread computes 16 cells.
// ---------------------------------------------------------------------------
__global__ __launch_bounds__(256, 1) void k_step(
    const f16* __restrict__ A, int lda, int K,
    const f16* __restrict__ W, int ldb,
    const float* __restrict__ bias,
    float* __restrict__ Cst,
    f16* __restrict__ Hout)
{
    __shared__ alignas(16) unsigned char smem[65536];
    const int hid0 = blockIdx.x * 32;
    const int bm0  = blockIdx.y * 128;
    f32x16 acc[2][2];
    gemm_core(A, lda, W, ldb, K, bm0, hid0, 2048, smem, acc);

    const int tid = threadIdx.x;
    const int wave = tid >> 6, wr = wave >> 1, wc = wave & 1;
    const int lane = tid & 63, l31 = lane & 31, hi = lane >> 5;
    float* G = (float*)smem;   // [128 rows][128 cols]; col = gate*32 + hid_l
    #pragma unroll
    for (int mt = 0; mt < 2; ++mt)
      #pragma unroll
      for (int nt = 0; nt < 2; ++nt) {
        const int col = wc * 64 + nt * 32 + l31;
        #pragma unroll
        for (int reg = 0; reg < 16; ++reg) {
          const int row = wr * 64 + mt * 32 + (reg & 3) + 8 * (reg >> 2) + 4 * hi;
          G[row * 128 + col] = acc[mt][nt][reg];
        }
      }
    __syncthreads();
    const int hl  = tid & 31;          // (j*256+tid)&31 == tid&31
    const int r8  = tid >> 5;          // 0..7
    const int hid = hid0 + hl;
    const float bI = bias[hid];
    const float bF = bias[2048 + hid];
    const float bG = bias[4096 + hid];
    const float bO = bias[6144 + hid];
    #pragma unroll
    for (int j = 0; j < 16; ++j) {
        const int row = j * 8 + r8;
        const float* g = G + row * 128;
        float iv = g[hl]      + bI;
        float fv = g[32 + hl] + bF;
        float gv = g[64 + hl] + bG;
        float ov = g[96 + hl] + bO;
        float si = 1.f / (1.f + __expf(-iv));
        float sf = 1.f / (1.f + __expf(-fv));
        float so = 1.f / (1.f + __expf(-ov));
        float tg = tanhf(gv);
        const size_t idx = (size_t)(bm0 + row) * 2048 + hid;
        float c = sf * Cst[idx] + si * tg;
        Cst[idx] = c;
        Hout[idx] = (f16)(so * tanhf(c));
    }
}

// out[b, t, d] = H[slot, b, :] @ W_out[d, :] + b_out[d];  t = t0 + slot
// One block covers all 128 output dims x 128 M-rows.
__global__ __launch_bounds__(256, 1) void k_out(
    const f16* __restrict__ Hbase,
    const f16* __restrict__ Wout,
    const float* __restrict__ bout,
    float* __restrict__ out, int t0)
{
    __shared__ alignas(16) unsigned char smem[65536];
    const int bm0 = blockIdx.y * 128;  // over M = depth*512
    f32x16 acc[2][2];
    gemm_core(Hbase, 2048, Wout, 2048, 2048, bm0, 0, 32, smem, acc);
    const int tid = threadIdx.x;
    const int wave = tid >> 6, wr = wave >> 1, wc = wave & 1;
    const int lane = tid & 63, l31 = lane & 31, hi = lane >> 5;
    #pragma unroll
    for (int mt = 0; mt < 2; ++mt)
      #pragma unroll
      for (int nt = 0; nt < 2; ++nt) {
        const int d = wc * 64 + nt * 32 + l31;
        const float bo = bout[d];
        #pragma unroll
        for (int reg = 0; reg < 16; ++reg) {
          const int row = wr * 64 + mt * 32 + (reg & 3) + 8 * (reg >> 2) + 4 * hi;
          const int m = bm0 + row;
          const int slot = m >> 9, b = m & 511;
          out[(size_t)b * 16384 + (t0 + slot) * 128 + d] = acc[mt][nt][reg] + bo;
        }
      }
}

// ---------------- prep kernels (run once per launch) ------------------------

__global__ void k_cast(const float* __restrict__ s, f16* __restrict__ d, int n)
{
    int i = blockIdx.x * 256 + threadIdx.x;
    if (i < n) d[i] = (f16)s[i];
}

__global__ void k_x0(const float* __restrict__ tgt, f16* __restrict__ x0)
{
    int i = blockIdx.x * 256 + threadIdx.x;  // 65536 total
    int b = i >> 7, d = i & 127;
    x0[i] = (f16)tgt[(size_t)b * 16384 + d];  // tgt[b, 0, d]
}

__global__ void k_bias(const float* __restrict__ bih, const float* __restrict__ bhh,
                       const float* __restrict__ Wih, const float* __restrict__ bout,
                       float* __restrict__ b0, float* __restrict__ bp)
{
    int r = blockIdx.x * 256 + threadIdx.x;
    if (r >= 8192) return;
    float s = bih[r] + bhh[r];
    float a = 0.f;
    for (int d = 0; d < 128; ++d) a += Wih[(size_t)r * 128 + d] * bout[d];
    b0[r] = s;        // step-0 bias
    bp[r] = s + a;    // recurrent bias (absorbs W_ih @ b_out)
}

// WoutT[k][d] = (f16) Wout[d][k]   (2048 x 128, MFMA B-operand for k_wcomb2)
__global__ void k_wt(const float* __restrict__ Wout, f16* __restrict__ WoutT)
{
    __shared__ float tile[64][65];
    const int k0 = blockIdx.x * 64;   // 32
    const int d0 = blockIdx.y * 64;   // 2
    const int tid = threadIdx.x;
    const int c = tid & 63, rr = tid >> 6;
    #pragma unroll
    for (int i = 0; i < 16; ++i) {
        int d = rr + i * 4;
        tile[d][c] = Wout[(size_t)(d0 + d) * 2048 + k0 + c];
    }
    __syncthreads();
    #pragma unroll
    for (int i = 0; i < 16; ++i) {
        int k = rr + i * 4;
        WoutT[(size_t)(k0 + k) * 128 + d0 + c] = (f16)tile[c][k];
    }
}

// Wc[r,k] = Whh[r,k] + W_ih[r,:] @ W_out[:,k]  via MFMA
__global__ __launch_bounds__(256, 1) void k_wcomb2(
    const f16* __restrict__ Wih16, const f16* __restrict__ WoutT,
    const float* __restrict__ Whh, f16* __restrict__ Wc)
{
    __shared__ alignas(16) unsigned char smem[65536];
    const int n0  = blockIdx.x * 128;  // 16 col-blocks over k
    const int bm0 = blockIdx.y * 128;  // 64 row-blocks over r
    f32x16 acc[2][2];
    gemm_core(Wih16, 128, WoutT, 128, 128, bm0, n0, 32, smem, acc);
    const int tid = threadIdx.x;
    const int wave = tid >> 6, wr = wave >> 1, wc = wave & 1;
    const int lane = tid & 63, l31 = lane & 31, hi = lane >> 5;
    #pragma unroll
    for (int mt = 0; mt < 2; ++mt)
      #pragma unroll
      for (int nt = 0; nt < 2; ++nt) {
        const int k = n0 + wc * 64 + nt * 32 + l31;
        #pragma unroll
        for (int reg = 0; reg < 16; ++reg) {
          const int row = wr * 64 + mt * 32 + (reg & 3) + 8 * (reg >> 2) + 4 * hi;
          const size_t r = (size_t)(bm0 + row);
          Wc[r * 2048 + k] = (f16)(acc[mt][nt][reg] + Whh[r * 2048 + k]);
        }
      }
}

// ---------------------------------------------------------------------------

extern "C" void kernel_launch(void* const* d_in, const int* in_sizes, int n_in,
                              void* d_out, int out_size, void* d_ws, size_t ws_size,
                              hipStream_t stream)
{
    const float* tgt  = (const float*)d_in[0];
    const float* Wih  = (const float*)d_in[1];
    const float* Whh  = (const float*)d_in[2];
    const float* bih  = (const float*)d_in[3];
    const float* bhh  = (const float*)d_in[4];
    const float* Wout = (const float*)d_in[5];
    const float* bout = (const float*)d_in[6];
    float* out = (float*)d_out;

    char* ws = (char*)d_ws;
    size_t off = 0;
    auto alloc = [&](size_t bytes) -> void* {
        void* p = ws + off;
        off += (bytes + 255) & ~(size_t)255;
        return p;
    };
    f16*   Wc     = (f16*)alloc((size_t)8192 * 2048 * 2);  // combined W_hh + W_ih*W_out
    f16*   Wih16  = (f16*)alloc((size_t)8192 * 128 * 2);
    f16*   Wout16 = (f16*)alloc((size_t)128 * 2048 * 2);
    f16*   WoutT  = (f16*)alloc((size_t)2048 * 128 * 2);
    f16*   x0     = (f16*)alloc((size_t)512 * 128 * 2);
    float* b0     = (float*)alloc(8192 * 4);
    float* bp     = (float*)alloc(8192 * 4);
    float* Cst    = (float*)alloc((size_t)512 * 2048 * 4);

    const size_t slotsz = (size_t)512 * 2048;  // elements per h snapshot
    int depth = 0;
    const int cands[7] = {128, 64, 32, 16, 8, 4, 2};
    for (int i = 0; i < 7; ++i)
        if (off + (size_t)cands[i] * slotsz * 2 <= ws_size) { depth = cands[i]; break; }
    if (depth == 0) return;  // workspace too small for any configuration
    f16* Hbuf = (f16*)alloc((size_t)depth * slotsz * 2);

    hipMemsetAsync(Cst, 0, (size_t)512 * 2048 * 4, stream);
    k_cast<<<dim3(4096), dim3(256), 0, stream>>>(Wih, Wih16, 1048576);
    k_cast<<<dim3(1024), dim3(256), 0, stream>>>(Wout, Wout16, 262144);
    k_wt<<<dim3(32, 2), dim3(256), 0, stream>>>(Wout, WoutT);
    k_x0<<<dim3(256), dim3(256), 0, stream>>>(tgt, x0);
    k_bias<<<dim3(32), dim3(256), 0, stream>>>(bih, bhh, Wih, bout, b0, bp);
    k_wcomb2<<<dim3(16, 64), dim3(256), 0, stream>>>(Wih16, WoutT, Whh, Wc);

    // step 0: gates = x0 @ W_ih^T + (b_ih+b_hh)  -> h^1 in slot 0
    k_step<<<dim3(64, 4), dim3(256), 0, stream>>>(x0, 128, 128, Wih16, 128, b0, Cst, Hbuf);
    // steps 1..127: gates = h @ W'^T + b'
    for (int s = 1; s < 128; ++s) {
        if ((s % depth) == 0)  // slots 0..depth-1 hold h^(s-depth+1..s) -> out t in [s-depth, s)
            k_out<<<dim3(1, depth * 4), dim3(256), 0, stream>>>(Hbuf, Wout16, bout, out, s - depth);
        k_step<<<dim3(64, 4), dim3(256), 0, stream>>>(
            Hbuf + (size_t)((s - 1) % depth) * slotsz, 2048, 2048, Wc, 2048, bp,
            Cst, Hbuf + (size_t)(s % depth) * slotsz);
    }
    k_out<<<dim3(1, depth * 4), dim3(256), 0, stream>>>(Hbuf, Wout16, bout, out, 128 - depth);
}